// Round 2
// baseline (1473.075 us; speedup 1.0000x reference)
//
#include <hip/hip_runtime.h>
#include <math.h>

// CapsuleLayer dynamic routing, fp32. B=256, I=2048, K=8, J=10, D=16.
// New path: thread = b (block covers all 256 batch rows), W fetched via wave-uniform
// SCALAR loads (readfirstlane-forced) -> no redundant vector traffic, no address VALU.
// Per round: logits_kernel (U recompute + in-register dot + per-thread softmax -> c[b,i,j])
// then sweight_kernel (U recompute, s[b,j,d] += c*U, atomics on distinct addresses).
// Routing logits are linear in accumulated v: round3 uses v1+v2. x transposed once to
// xT[i,b,k] for coalescing. k-contraction packed as float2 -> v_pk_fma_f32.
//
// ws layout (new): s_acc[40960] | vT[40960] | xT[4194304] | cT[5242880]  = 38.1 MB
// Falls back to the previous (passing, 365us) path if ws_size is too small.

typedef float v2f __attribute__((ext_vector_type(2)));

#define BB 256
#define II 2048
#define KK 8
#define JJ 10
#define DD 16

#define ITL 2    // i's per logits block (grid 1024)
#define ITS 16   // i's per sweight block (grid 128 x 10)

__global__ __launch_bounds__(256) void zero_kernel(float* __restrict__ p, int n) {
    int idx = blockIdx.x * blockDim.x + threadIdx.x;
    if (idx < n) p[idx] = 0.f;
}

// x[b,i,k] -> xT[i,b,k], LDS-tiled (tile 32b x 8i), coalesced both sides.
__global__ __launch_bounds__(256) void transpose_kernel(const float* __restrict__ x,
                                                        float* __restrict__ xT) {
    __shared__ float4 tile[8 * 66];  // [li][lb*2+q], stride 66 float4s to spread banks
    const int t = threadIdx.x;
    const int b0 = blockIdx.y * 32, i0 = blockIdx.x * 8;
    {
        const int lb = t >> 3, li = t & 7;
        const float4* src = (const float4*)(x + ((b0 + lb) * II + (i0 + li)) * KK);
        tile[li * 66 + lb * 2 + 0] = src[0];
        tile[li * 66 + lb * 2 + 1] = src[1];
    }
    __syncthreads();
    {
        const int ri = t >> 5, rb = t & 31;
        float4* dst = (float4*)(xT + ((i0 + ri) * BB + (b0 + rb)) * KK);
        dst[0] = tile[ri * 66 + rb * 2 + 0];
        dst[1] = tile[ri * 66 + rb * 2 + 1];
    }
}

// c[b,i,j] = softmax_j( sum_d vT[j,d,b] * U[b,i,j,d] ), U recomputed from scalar W.
__global__ __launch_bounds__(256) void logits_kernel(const float* __restrict__ xT,
                                                     const float* __restrict__ W,
                                                     const float* __restrict__ vT,
                                                     float* __restrict__ cT) {
    __shared__ float lbuf[ITL * JJ * BB];  // per-thread scratch column, no barrier needed
    const int b = threadIdx.x;
    const int i0 = blockIdx.x * ITL;

    for (int j = 0; j < JJ; ++j) {
        float vj[DD];
#pragma unroll
        for (int d = 0; d < DD; ++d) vj[d] = vT[(j * DD + d) * BB + b];
#pragma unroll
        for (int ii = 0; ii < ITL; ++ii) {
            const int i = i0 + ii;
            const float4* xp = (const float4*)(xT + (i * BB + b) * KK);
            const float4 xa = xp[0], xb4 = xp[1];
            v2f x2[4];
            x2[0] = (v2f){xa.x, xa.y};  x2[1] = (v2f){xa.z, xa.w};
            x2[2] = (v2f){xb4.x, xb4.y}; x2[3] = (v2f){xb4.z, xb4.w};
            const int wof = __builtin_amdgcn_readfirstlane((j * II + i) << 7);
            const v2f* wp = (const v2f*)(W + wof);
            float lg0 = 0.f, lg1 = 0.f;
#pragma unroll
            for (int d = 0; d < DD; d += 2) {
                v2f u2 = wp[4 * d + 0] * x2[0];
                u2 += wp[4 * d + 1] * x2[1];
                u2 += wp[4 * d + 2] * x2[2];
                u2 += wp[4 * d + 3] * x2[3];
                lg0 += vj[d] * (u2.x + u2.y);
                v2f w2 = wp[4 * d + 4] * x2[0];
                w2 += wp[4 * d + 5] * x2[1];
                w2 += wp[4 * d + 6] * x2[2];
                w2 += wp[4 * d + 7] * x2[3];
                lg1 += vj[d + 1] * (w2.x + w2.y);
            }
            lbuf[(ii * JJ + j) * BB + b] = lg0 + lg1;
        }
    }
#pragma unroll
    for (int ii = 0; ii < ITL; ++ii) {
        float e[JJ];
        float mx = -1e30f;
#pragma unroll
        for (int j = 0; j < JJ; ++j) {
            e[j] = lbuf[(ii * JJ + j) * BB + b];
            mx = fmaxf(mx, e[j]);
        }
        float sum = 0.f;
#pragma unroll
        for (int j = 0; j < JJ; ++j) { e[j] = __expf(e[j] - mx); sum += e[j]; }
        const float inv = 1.f / sum;
#pragma unroll
        for (int j = 0; j < JJ; ++j)
            cT[((i0 + ii) * JJ + j) * BB + b] = e[j] * inv;
    }
}

// s_acc[b,j,d] += sum_i c[b,i,j] * U[b,i,j,d]   (USE_C=0: c == 1, used for round 1)
template <int USE_C>
__global__ __launch_bounds__(256) void sweight_kernel(const float* __restrict__ xT,
                                                      const float* __restrict__ W,
                                                      const float* __restrict__ cT,
                                                      float* __restrict__ s_acc) {
    const int b = threadIdx.x;
    const int j = blockIdx.y;
    const int i0 = blockIdx.x * ITS;
    v2f acc2[DD];
#pragma unroll
    for (int d = 0; d < DD; ++d) acc2[d] = (v2f){0.f, 0.f};

#pragma unroll 2
    for (int ii = 0; ii < ITS; ++ii) {
        const int i = i0 + ii;
        const float4* xp = (const float4*)(xT + (i * BB + b) * KK);
        const float4 xa = xp[0], xb4 = xp[1];
        v2f x2[4];
        x2[0] = (v2f){xa.x, xa.y};  x2[1] = (v2f){xa.z, xa.w};
        x2[2] = (v2f){xb4.x, xb4.y}; x2[3] = (v2f){xb4.z, xb4.w};
        v2f c2 = (v2f){1.f, 1.f};
        if (USE_C) {
            const float c = cT[(i * JJ + j) * BB + b];
            c2 = (v2f){c, c};
        }
        const int wof = __builtin_amdgcn_readfirstlane((j * II + i) << 7);
        const v2f* wp = (const v2f*)(W + wof);
#pragma unroll
        for (int d = 0; d < DD; ++d) {
            v2f u2 = wp[4 * d + 0] * x2[0];
            u2 += wp[4 * d + 1] * x2[1];
            u2 += wp[4 * d + 2] * x2[2];
            u2 += wp[4 * d + 3] * x2[3];
            if (USE_C) acc2[d] += c2 * u2;
            else       acc2[d] += u2;
        }
    }
#pragma unroll
    for (int d = 0; d < DD; ++d)
        atomicAdd(&s_acc[(b * JJ + j) * DD + d], acc2[d].x + acc2[d].y);
}

// v = squash(scale*s); dst either transposed vT[j,d,b] (routing) or out[b,j,d] (final).
__global__ __launch_bounds__(256) void squash_kernel(float* __restrict__ s_acc,
                                                     float* __restrict__ dst, float scale,
                                                     int add_to_dst, int zero_src,
                                                     int transposed) {
    int idx = blockIdx.x * blockDim.x + threadIdx.x;
    if (idx >= BB * JJ) return;
    float s[DD];
    float ss = 0.f;
#pragma unroll
    for (int d = 0; d < DD; ++d) {
        s[d] = s_acc[idx * DD + d] * scale;
        ss += s[d] * s[d];
    }
    const float coef = ss / (1.f + ss) / sqrtf(ss + 1e-7f);
    const int bq = idx / JJ, j = idx % JJ;
#pragma unroll
    for (int d = 0; d < DD; ++d) {
        const float vv = coef * s[d];
        const int off = transposed ? ((j * DD + d) * BB + bq) : (idx * DD + d);
        if (add_to_dst) dst[off] += vv;
        else            dst[off] = vv;
        if (zero_src)   s_acc[idx * DD + d] = 0.f;
    }
}

// ---------------- fallback path (previous passing kernel, 365us) ----------------
#define IT_OLD 32
#define BT_OLD 16

__global__ __launch_bounds__(256) void round1_old(const float* __restrict__ x,
                                                  const float* __restrict__ W,
                                                  float* __restrict__ s_acc) {
    const int t = threadIdx.x;
    const int d = t & 15;
    const int bq = t >> 4;
    const int b = blockIdx.y * BT_OLD + bq;
    const int i0 = blockIdx.x * IT_OLD;
    float acc[JJ];
#pragma unroll
    for (int j = 0; j < JJ; ++j) acc[j] = 0.f;
    for (int ii = 0; ii < IT_OLD; ++ii) {
        const int i = i0 + ii;
        const float* xp = x + ((b * II) + i) * KK;
        const float4 xa = *(const float4*)(xp);
        const float4 xb = *(const float4*)(xp + 4);
#pragma unroll
        for (int j = 0; j < JJ; ++j) {
            const float* wp = W + (((j * II + i) * DD + d) * KK);
            const float4 w0 = *(const float4*)(wp);
            const float4 w1 = *(const float4*)(wp + 4);
            acc[j] += w0.x*xa.x + w0.y*xa.y + w0.z*xa.z + w0.w*xa.w
                    + w1.x*xb.x + w1.y*xb.y + w1.z*xb.z + w1.w*xb.w;
        }
    }
#pragma unroll
    for (int j = 0; j < JJ; ++j)
        atomicAdd(&s_acc[(b * JJ + j) * DD + d], acc[j]);
}

__global__ __launch_bounds__(256) void round_old(const float* __restrict__ x,
                                                 const float* __restrict__ W,
                                                 const float* __restrict__ v,
                                                 float* __restrict__ s_acc) {
    const int t = threadIdx.x;
    const int d = t & 15;
    const int bq = t >> 4;
    const int b = blockIdx.y * BT_OLD + bq;
    const int i0 = blockIdx.x * IT_OLD;
    float vr[JJ], acc[JJ];
#pragma unroll
    for (int j = 0; j < JJ; ++j) {
        vr[j] = v[(b * JJ + j) * DD + d];
        acc[j] = 0.f;
    }
    for (int ii = 0; ii < IT_OLD; ++ii) {
        const int i = i0 + ii;
        const float* xp = x + ((b * II) + i) * KK;
        const float4 xa = *(const float4*)(xp);
        const float4 xb = *(const float4*)(xp + 4);
        float U[JJ], L[JJ];
#pragma unroll
        for (int j = 0; j < JJ; ++j) {
            const float* wp = W + (((j * II + i) * DD + d) * KK);
            const float4 w0 = *(const float4*)(wp);
            const float4 w1 = *(const float4*)(wp + 4);
            U[j] = w0.x*xa.x + w0.y*xa.y + w0.z*xa.z + w0.w*xa.w
                 + w1.x*xb.x + w1.y*xb.y + w1.z*xb.z + w1.w*xb.w;
            L[j] = vr[j] * U[j];
        }
#pragma unroll
        for (int m = 8; m >= 1; m >>= 1) {
#pragma unroll
            for (int j = 0; j < JJ; ++j) L[j] += __shfl_xor(L[j], m, 64);
        }
        float mx = L[0];
#pragma unroll
        for (int j = 1; j < JJ; ++j) mx = fmaxf(mx, L[j]);
        float sum = 0.f;
#pragma unroll
        for (int j = 0; j < JJ; ++j) { L[j] = __expf(L[j] - mx); sum += L[j]; }
        const float inv = 1.f / sum;
#pragma unroll
        for (int j = 0; j < JJ; ++j) acc[j] += (L[j] * inv) * U[j];
    }
#pragma unroll
    for (int j = 0; j < JJ; ++j)
        atomicAdd(&s_acc[(b * JJ + j) * DD + d], acc[j]);
}

extern "C" void kernel_launch(void* const* d_in, const int* in_sizes, int n_in,
                              void* d_out, int out_size, void* d_ws, size_t ws_size,
                              hipStream_t stream) {
    const float* x = (const float*)d_in[0];   // [B, I, K]
    const float* W = (const float*)d_in[1];   // [J, I, D, K]
    float* out = (float*)d_out;               // [B, J, D]

    float* s_acc = (float*)d_ws;              // [B*J*D]
    float* vT    = s_acc + BB * JJ * DD;      // [J*D*B]
    float* xT    = vT + BB * JJ * DD;         // [I*B*K]
    float* cT    = xT + II * BB * KK;         // [I*J*B]
    const size_t need = (size_t)(2 * BB * JJ * DD + II * BB * KK + (size_t)II * JJ * BB) * 4;

    const int NS = BB * JJ * DD;

    if (ws_size >= need) {
        zero_kernel<<<(NS + 255) / 256, 256, 0, stream>>>(s_acc, NS);
        transpose_kernel<<<dim3(II / 8, BB / 32), 256, 0, stream>>>(x, xT);

        dim3 sg(II / ITS, JJ);   // 128 x 10
        // round 1: uniform c (1/J folded into squash scale)
        sweight_kernel<0><<<sg, 256, 0, stream>>>(xT, W, nullptr, s_acc);
        squash_kernel<<<(BB * JJ + 255) / 256, 256, 0, stream>>>(s_acc, vT, 0.1f, 0, 1, 1);
        // round 2: logits = v1 . U
        logits_kernel<<<II / ITL, 256, 0, stream>>>(xT, W, vT, cT);
        sweight_kernel<1><<<sg, 256, 0, stream>>>(xT, W, cT, s_acc);
        squash_kernel<<<(BB * JJ + 255) / 256, 256, 0, stream>>>(s_acc, vT, 1.0f, 1, 1, 1);
        // round 3: logits = (v1+v2) . U
        logits_kernel<<<II / ITL, 256, 0, stream>>>(xT, W, vT, cT);
        sweight_kernel<1><<<sg, 256, 0, stream>>>(xT, W, cT, s_acc);
        squash_kernel<<<(BB * JJ + 255) / 256, 256, 0, stream>>>(s_acc, out, 1.0f, 0, 0, 0);
    } else {
        // fallback: previous passing path (v_buf in [b,j,d] layout)
        float* v_buf = vT;
        dim3 rg(II / IT_OLD, BB / BT_OLD);
        zero_kernel<<<(NS + 255) / 256, 256, 0, stream>>>(s_acc, NS);
        round1_old<<<rg, 256, 0, stream>>>(x, W, s_acc);
        squash_kernel<<<(BB * JJ + 255) / 256, 256, 0, stream>>>(s_acc, v_buf, 0.1f, 0, 1, 0);
        round_old<<<rg, 256, 0, stream>>>(x, W, v_buf, s_acc);
        squash_kernel<<<(BB * JJ + 255) / 256, 256, 0, stream>>>(s_acc, v_buf, 1.0f, 1, 1, 0);
        round_old<<<rg, 256, 0, stream>>>(x, W, v_buf, s_acc);
        squash_kernel<<<(BB * JJ + 255) / 256, 256, 0, stream>>>(s_acc, out, 1.0f, 0, 0, 0);
    }
}

// Round 3
// 198.162 us; speedup vs baseline: 7.4337x; 7.4337x over previous
//
#include <hip/hip_runtime.h>
#include <math.h>

// CapsuleLayer dynamic routing, fp32 in/out. B=256, I=2048, K=8, J=10, D=16.
// MFMA path: per (i, j, 16-b tile) one mfma_f32_16x16x32_bf16 computes
// U[d,b] = sum_k W[j,i,d,k] * x[b,i,k]  (k padded 8->32; round 1 packs 4 i's into K=32).
// C/D layout (verified, guide S3): col = lane&15 = b, row = (lane>>4)*4 + reg = d.
// A layout: A[m=lane&15][kc=quad*8+r]; B mirrors with n=lane&15.
// Logits = per-lane dot(vfrag, U) + shfl_xor(16,32); softmax over J in registers;
// s update = c*U accumulate in C-layout; LDS block-reduce (4 waves -> 1) then atomics.
// Routing logits are linear in accumulated v (round 3 uses v1+v2) -> no logit buffer.
//
// ws: s_acc f32[40960] | vT f32[40960] | xTb bf16[I*B*K] | Wb bf16[J*I*D*K]  (~13.3 MB)

#define BB 256
#define II 2048
#define KK 8
#define JJ 10
#define DD 16

typedef __attribute__((ext_vector_type(4))) float f32x4;
typedef __attribute__((ext_vector_type(8))) short short8;

__device__ __forceinline__ short f2bf(float f) {
    union { float f; unsigned u; } v; v.f = f;
    unsigned r = v.u + 0x7FFFu + ((v.u >> 16) & 1u);   // RNE
    return (short)(r >> 16);
}

__global__ __launch_bounds__(256) void zero_kernel(float* __restrict__ p, int n) {
    int idx = blockIdx.x * blockDim.x + threadIdx.x;
    if (idx < n) p[idx] = 0.f;
}

// W fp32 [j,i,d,k] -> Wb bf16 same layout (k contiguous = A-frag rows). 16B/lane stores.
__global__ __launch_bounds__(256) void cast_w_kernel(const float* __restrict__ W,
                                                     short* __restrict__ Wb) {
    const int idx = blockIdx.x * blockDim.x + threadIdx.x;   // one 8-elem row each
    const float4* src = (const float4*)(W + (size_t)idx * 8);
    const float4 a = src[0], b = src[1];
    short8 o;
    o[0] = f2bf(a.x); o[1] = f2bf(a.y); o[2] = f2bf(a.z); o[3] = f2bf(a.w);
    o[4] = f2bf(b.x); o[5] = f2bf(b.y); o[6] = f2bf(b.z); o[7] = f2bf(b.w);
    *(short8*)(Wb + (size_t)idx * 8) = o;
}

// x fp32 [b,i,k] -> xTb bf16 [i,b,k], LDS-tiled, coalesced both sides.
__global__ __launch_bounds__(256) void trans_x_kernel(const float* __restrict__ x,
                                                      short* __restrict__ xTb) {
    __shared__ float4 tile[8 * 66];
    const int t = threadIdx.x;
    const int b0 = blockIdx.y * 32, i0 = blockIdx.x * 8;
    {
        const int lb = t >> 3, li = t & 7;
        const float4* src = (const float4*)(x + ((b0 + lb) * II + (i0 + li)) * KK);
        tile[li * 66 + lb * 2 + 0] = src[0];
        tile[li * 66 + lb * 2 + 1] = src[1];
    }
    __syncthreads();
    {
        const int ri = t >> 5, rb = t & 31;
        const float4 p0 = tile[ri * 66 + rb * 2 + 0];
        const float4 p1 = tile[ri * 66 + rb * 2 + 1];
        short8 o;
        o[0] = f2bf(p0.x); o[1] = f2bf(p0.y); o[2] = f2bf(p0.z); o[3] = f2bf(p0.w);
        o[4] = f2bf(p1.x); o[5] = f2bf(p1.y); o[6] = f2bf(p1.z); o[7] = f2bf(p1.w);
        *(short8*)(xTb + ((size_t)(i0 + ri) * BB + (b0 + rb)) * KK) = o;
    }
}

// One routing round. grid (32, 16btiles), block 256 (4 waves), 16 i per wave.
// USE_C=0: round 1, uniform coupling (1/J folded into squash scale), 4 i packed per MFMA.
template <int USE_C>
__global__ __launch_bounds__(256, 2) void round_mfma(
    const short* __restrict__ xTb, const short* __restrict__ Wb,
    const float* __restrict__ vT, float* __restrict__ s_acc)
{
    __shared__ float s_lds[4][JJ * DD * 16];
    const int t = threadIdx.x;
    const int lane = t & 63, wv = t >> 6;
    const int col = lane & 15, q = lane >> 4;
    const int b0 = blockIdx.y * 16;
    const int ibase = (blockIdx.x * 4 + wv) * 16;

    f32x4 sfrag[JJ];
#pragma unroll
    for (int j = 0; j < JJ; ++j) sfrag[j] = (f32x4){0.f, 0.f, 0.f, 0.f};

    if (USE_C) {
        float vfrag[JJ][4];
#pragma unroll
        for (int j = 0; j < JJ; ++j)
#pragma unroll
            for (int r = 0; r < 4; ++r)
                vfrag[j][r] = vT[(j * DD + q * 4 + r) * BB + b0 + col];

        short8 A[JJ];
        short8 Bf = (short8){0, 0, 0, 0, 0, 0, 0, 0};
#pragma unroll
        for (int j = 0; j < JJ; ++j) A[j] = (short8){0, 0, 0, 0, 0, 0, 0, 0};

        for (int ii = 0; ii < 16; ++ii) {
            const int i = ibase + ii;
            if (q == 0) {   // kc 0..7 real, quads 1..3 stay zero (k-pad 8->32)
                Bf = *(const short8*)(xTb + ((size_t)i * BB + b0 + col) * KK);
#pragma unroll
                for (int j = 0; j < JJ; ++j)
                    A[j] = *(const short8*)(Wb + (((size_t)j * II + i) * DD + col) * KK);
            }
            f32x4 U[JJ];
#pragma unroll
            for (int j = 0; j < JJ; ++j)
                U[j] = __builtin_amdgcn_mfma_f32_16x16x32_bf16(
                    A[j], Bf, (f32x4){0.f, 0.f, 0.f, 0.f}, 0, 0, 0);
            float L[JJ];
#pragma unroll
            for (int j = 0; j < JJ; ++j)
                L[j] = vfrag[j][0] * U[j][0] + vfrag[j][1] * U[j][1]
                     + vfrag[j][2] * U[j][2] + vfrag[j][3] * U[j][3];
#pragma unroll
            for (int j = 0; j < JJ; ++j) {   // reduce over the 4 d-quads (same b col)
                L[j] += __shfl_xor(L[j], 16, 64);
                L[j] += __shfl_xor(L[j], 32, 64);
            }
            float mx = L[0];
#pragma unroll
            for (int j = 1; j < JJ; ++j) mx = fmaxf(mx, L[j]);
            float sum = 0.f;
#pragma unroll
            for (int j = 0; j < JJ; ++j) { L[j] = __expf(L[j] - mx); sum += L[j]; }
            const float inv = 1.f / sum;
#pragma unroll
            for (int j = 0; j < JJ; ++j) {
                const float c = L[j] * inv;
#pragma unroll
                for (int r = 0; r < 4; ++r) sfrag[j][r] += c * U[j][r];
            }
        }
    } else {
        // round 1: sum_i U. Pack 4 i's per MFMA: kc = q*8 + k  ->  i_local = q.
        for (int s = 0; s < 4; ++s) {
            const int i = ibase + s * 4 + q;
            const short8 Bf = *(const short8*)(xTb + ((size_t)i * BB + b0 + col) * KK);
#pragma unroll
            for (int j = 0; j < JJ; ++j) {
                const short8 A = *(const short8*)(Wb + (((size_t)j * II + i) * DD + col) * KK);
                sfrag[j] = __builtin_amdgcn_mfma_f32_16x16x32_bf16(A, Bf, sfrag[j], 0, 0, 0);
            }
        }
    }

    // block reduce: 4 waves -> LDS -> one atomicAdd per (b,j,d)
#pragma unroll
    for (int j = 0; j < JJ; ++j)
#pragma unroll
        for (int r = 0; r < 4; ++r)
            s_lds[wv][(j * DD + q * 4 + r) * 16 + col] = sfrag[j][r];
    __syncthreads();
#pragma unroll
    for (int l0 = 0; l0 < JJ; ++l0) {
        const int l = l0 * 256 + t;   // l = j*256 + d*16 + bcol
        const float v = s_lds[0][l] + s_lds[1][l] + s_lds[2][l] + s_lds[3][l];
        const int j = l >> 8, rem = l & 255;
        const int d = rem >> 4, bc = rem & 15;
        atomicAdd(&s_acc[((b0 + bc) * JJ + j) * DD + d], v);
    }
}

// v = squash(scale*s); dst transposed vT[j,d,b] (routing) or out[b,j,d] (final).
__global__ __launch_bounds__(256) void squash_kernel(float* __restrict__ s_acc,
                                                     float* __restrict__ dst, float scale,
                                                     int add_to_dst, int zero_src,
                                                     int transposed) {
    int idx = blockIdx.x * blockDim.x + threadIdx.x;
    if (idx >= BB * JJ) return;
    float s[DD];
    float ss = 0.f;
#pragma unroll
    for (int d = 0; d < DD; ++d) {
        s[d] = s_acc[idx * DD + d] * scale;
        ss += s[d] * s[d];
    }
    const float coef = ss / (1.f + ss) / sqrtf(ss + 1e-7f);
    const int bq = idx / JJ, j = idx % JJ;
#pragma unroll
    for (int d = 0; d < DD; ++d) {
        const float vv = coef * s[d];
        const int off = transposed ? ((j * DD + d) * BB + bq) : (idx * DD + d);
        if (add_to_dst) dst[off] += vv;
        else            dst[off] = vv;
        if (zero_src)   s_acc[idx * DD + d] = 0.f;
    }
}

// ---------------- fallback path (round-1 passing kernel, 365us) ----------------
#define IT_OLD 32
#define BT_OLD 16

__global__ __launch_bounds__(256) void round1_old(const float* __restrict__ x,
                                                  const float* __restrict__ W,
                                                  float* __restrict__ s_acc) {
    const int t = threadIdx.x;
    const int d = t & 15;
    const int bq = t >> 4;
    const int b = blockIdx.y * BT_OLD + bq;
    const int i0 = blockIdx.x * IT_OLD;
    float acc[JJ];
#pragma unroll
    for (int j = 0; j < JJ; ++j) acc[j] = 0.f;
    for (int ii = 0; ii < IT_OLD; ++ii) {
        const int i = i0 + ii;
        const float* xp = x + ((b * II) + i) * KK;
        const float4 xa = *(const float4*)(xp);
        const float4 xb = *(const float4*)(xp + 4);
#pragma unroll
        for (int j = 0; j < JJ; ++j) {
            const float* wp = W + (((j * II + i) * DD + d) * KK);
            const float4 w0 = *(const float4*)(wp);
            const float4 w1 = *(const float4*)(wp + 4);
            acc[j] += w0.x*xa.x + w0.y*xa.y + w0.z*xa.z + w0.w*xa.w
                    + w1.x*xb.x + w1.y*xb.y + w1.z*xb.z + w1.w*xb.w;
        }
    }
#pragma unroll
    for (int j = 0; j < JJ; ++j)
        atomicAdd(&s_acc[(b * JJ + j) * DD + d], acc[j]);
}

__global__ __launch_bounds__(256) void round_old(const float* __restrict__ x,
                                                 const float* __restrict__ W,
                                                 const float* __restrict__ v,
                                                 float* __restrict__ s_acc) {
    const int t = threadIdx.x;
    const int d = t & 15;
    const int bq = t >> 4;
    const int b = blockIdx.y * BT_OLD + bq;
    const int i0 = blockIdx.x * IT_OLD;
    float vr[JJ], acc[JJ];
#pragma unroll
    for (int j = 0; j < JJ; ++j) {
        vr[j] = v[(b * JJ + j) * DD + d];
        acc[j] = 0.f;
    }
    for (int ii = 0; ii < IT_OLD; ++ii) {
        const int i = i0 + ii;
        const float* xp = x + ((b * II) + i) * KK;
        const float4 xa = *(const float4*)(xp);
        const float4 xb = *(const float4*)(xp + 4);
        float U[JJ], L[JJ];
#pragma unroll
        for (int j = 0; j < JJ; ++j) {
            const float* wp = W + (((j * II + i) * DD + d) * KK);
            const float4 w0 = *(const float4*)(wp);
            const float4 w1 = *(const float4*)(wp + 4);
            U[j] = w0.x*xa.x + w0.y*xa.y + w0.z*xa.z + w0.w*xa.w
                 + w1.x*xb.x + w1.y*xb.y + w1.z*xb.z + w1.w*xb.w;
            L[j] = vr[j] * U[j];
        }
#pragma unroll
        for (int m = 8; m >= 1; m >>= 1) {
#pragma unroll
            for (int j = 0; j < JJ; ++j) L[j] += __shfl_xor(L[j], m, 64);
        }
        float mx = L[0];
#pragma unroll
        for (int j = 1; j < JJ; ++j) mx = fmaxf(mx, L[j]);
        float sum = 0.f;
#pragma unroll
        for (int j = 0; j < JJ; ++j) { L[j] = __expf(L[j] - mx); sum += L[j]; }
        const float inv = 1.f / sum;
#pragma unroll
        for (int j = 0; j < JJ; ++j) acc[j] += (L[j] * inv) * U[j];
    }
#pragma unroll
    for (int j = 0; j < JJ; ++j)
        atomicAdd(&s_acc[(b * JJ + j) * DD + d], acc[j]);
}

extern "C" void kernel_launch(void* const* d_in, const int* in_sizes, int n_in,
                              void* d_out, int out_size, void* d_ws, size_t ws_size,
                              hipStream_t stream) {
    const float* x = (const float*)d_in[0];   // [B, I, K]
    const float* W = (const float*)d_in[1];   // [J, I, D, K]
    float* out = (float*)d_out;               // [B, J, D]

    float* s_acc = (float*)d_ws;                       // 40960 f32
    float* vT    = s_acc + BB * JJ * DD;               // 40960 f32
    short* xTb   = (short*)(vT + BB * JJ * DD);        // I*B*K bf16
    short* Wb    = xTb + (size_t)II * BB * KK;         // J*I*D*K bf16
    const size_t need = (size_t)(2 * BB * JJ * DD) * 4
                      + ((size_t)II * BB * KK + (size_t)JJ * II * DD * KK) * 2;

    const int NS = BB * JJ * DD;

    if (ws_size >= need) {
        zero_kernel<<<(NS + 255) / 256, 256, 0, stream>>>(s_acc, NS);
        cast_w_kernel<<<(JJ * II * DD * KK / 8) / 256, 256, 0, stream>>>(W, Wb);
        trans_x_kernel<<<dim3(II / 8, BB / 32), 256, 0, stream>>>(x, xTb);

        dim3 rg(32, 16);
        // round 1: uniform c (1/J folded into squash scale)
        round_mfma<0><<<rg, 256, 0, stream>>>(xTb, Wb, vT, s_acc);
        squash_kernel<<<(BB * JJ + 255) / 256, 256, 0, stream>>>(s_acc, vT, 0.1f, 0, 1, 1);
        // round 2: logits = v1 . U
        round_mfma<1><<<rg, 256, 0, stream>>>(xTb, Wb, vT, s_acc);
        squash_kernel<<<(BB * JJ + 255) / 256, 256, 0, stream>>>(s_acc, vT, 1.0f, 1, 1, 1);
        // round 3: logits = (v1+v2) . U
        round_mfma<1><<<rg, 256, 0, stream>>>(xTb, Wb, vT, s_acc);
        squash_kernel<<<(BB * JJ + 255) / 256, 256, 0, stream>>>(s_acc, out, 1.0f, 0, 0, 0);
    } else {
        // fallback: round-1 passing path
        float* v_buf = vT;
        dim3 rg(II / IT_OLD, BB / BT_OLD);
        zero_kernel<<<(NS + 255) / 256, 256, 0, stream>>>(s_acc, NS);
        round1_old<<<rg, 256, 0, stream>>>(x, W, s_acc);
        squash_kernel<<<(BB * JJ + 255) / 256, 256, 0, stream>>>(s_acc, v_buf, 0.1f, 0, 1, 0);
        round_old<<<rg, 256, 0, stream>>>(x, W, v_buf, s_acc);
        squash_kernel<<<(BB * JJ + 255) / 256, 256, 0, stream>>>(s_acc, v_buf, 1.0f, 1, 1, 0);
        round_old<<<rg, 256, 0, stream>>>(x, W, v_buf, s_acc);
        squash_kernel<<<(BB * JJ + 255) / 256, 256, 0, stream>>>(s_acc, out, 1.0f, 0, 0, 0);
    }
}